// Round 13
// baseline (79.153 us; speedup 1.0000x reference)
//
#include <hip/hip_runtime.h>
#include <hip/hip_cooperative_groups.h>
#include <math.h>

namespace cg = cooperative_groups;

#define IMG_H 256
#define IMG_W 256
#define NBATCH 32
#define NPER 4096
#define NPTS (NBATCH * NPER)
#define STRIP 16
#define NSTRIPS (IMG_H / STRIP)      // 16
#define THREADS 1024
#define NWAVES (THREADS / 64)        // 16
#define NBLOCKS (NSTRIPS * NBATCH)   // 512 = 2 blocks/CU x 256 CU (co-resident)
#define PADL 19
#define ROWW 299                     // mod 32 = 11 -> adjacent rows on distant banks
#define CANVAS_W (STRIP * ROWW)      // 4784 words (19.1 KB)
#define KC  0.15707964f              // pi/20
#define KC3 0.47123890f              // 3*KC
#define TMAX 2.4674011f              // (pi/2)^2 : poly(t) >= 3.3e-5 on [0,TMAX]
#define CAP 2048                     // LDS queue entries (worst center strip ~900)

// d_ws layout: [0, 4096) f32 zmin[512] + zmax[512] partials.

// 8 views, rows 0..2 of M (row 3 is [0,0,0,1] -> w==1).
struct Mats { float m[8][12]; };

static void build_mats(float out[8][12]) {
  static const double EYES[8][3] = {
    {-1,-1,-1},{-1,-1, 1},{-1, 1,-1},{-1, 1, 1},
    { 1,-1,-1},{ 1,-1, 1},{ 1, 1,-1},{ 1, 1, 1}};
  for (int v = 0; v < 8; ++v) {
    const double* e = EYES[v];
    double en = sqrt(e[0]*e[0] + e[1]*e[1] + e[2]*e[2]);
    if (en < 1e-6) en = 1e-6;
    double z[3] = {e[0]/en, e[1]/en, e[2]/en};
    double x[3] = {-z[1], z[0], 0.0};
    double xn = sqrt(x[0]*x[0] + x[1]*x[1]);
    if (xn < 1e-6) xn = 1e-6;
    x[0] /= xn; x[1] /= xn; x[2] = 0.0;
    double y[3] = {z[1]*x[2] - z[2]*x[1],
                   z[2]*x[0] - z[0]*x[2],
                   z[0]*x[1] - z[1]*x[0]};
    const double s  = 1.5;
    const double pz = -2.0 / (10.0 - 0.1);
    const double c3 = (10.0 + 0.1) / (10.0 - 0.1);
    double dxe = x[0]*e[0] + x[1]*e[1] + x[2]*e[2];
    double dye = y[0]*e[0] + y[1]*e[1] + y[2]*e[2];
    double dze = z[0]*e[0] + z[1]*e[1] + z[2]*e[2];
    out[v][0] = (float)(s*x[0]); out[v][1] = (float)(s*x[1]);
    out[v][2] = (float)(s*x[2]); out[v][3] = (float)(-s*dxe);
    out[v][4] = (float)(s*y[0]); out[v][5] = (float)(s*y[1]);
    out[v][6] = (float)(s*y[2]); out[v][7] = (float)(-s*dye);
    out[v][8] = (float)(pz*z[0]); out[v][9] = (float)(pz*z[1]);
    out[v][10] = (float)(pz*z[2]); out[v][11] = (float)(-pz*dze + c3);
  }
}

// ONE cooperative kernel, one dispatch.
// Phase 0: each block reduces zmin/zmax over its own 256-point slice ->
//          partials in d_ws; grid.sync().
// Phase 1: wave 0 reduces the 512+512 partials while all threads init canvas.
// Phase A: block sweeps its batch's 4096 points (float2x3 vector loads),
//          ballot-compacting strip hits into an LDS float4 queue with feat
//          precomputed.
// Phase B: waves drain the queue cooperatively: 60 lanes = 3 rows x 20 cols
//          over the 20x20 effective footprint, branchless inner loop
//          (clamped poly, junk <= 1.3e-4 << 1.9e-2 threshold), incremental
//          dx/pointer, idempotent row-clamp tail, pad-protected canvas.
// Zero global atomics, zero global intermediates (except 4 KB partials).
__global__ __launch_bounds__(THREADS, 8)
void splat_coop(const float* __restrict__ data,
                const int* __restrict__ view_id,
                Mats mats, float* __restrict__ red,
                float* __restrict__ out) {
  __shared__ unsigned int canvas[CANVAS_W];   // 19136 B
  __shared__ float4 q4[CAP];                  // 32 KB
  __shared__ int qcnt;
  __shared__ float zred[2];
  __shared__ float smn[4], smx[4];

  const int tid  = threadIdx.x;
  const int lane = tid & 63;
  const int wid  = tid >> 6;
  const int b    = blockIdx.y;
  const int strip = (b < 16) ? (int)blockIdx.x : (15 - (int)blockIdx.x);
  const int si0  = strip * STRIP;
  const int lin  = (int)blockIdx.y * NSTRIPS + (int)blockIdx.x;

  const int v = (*view_id) & 7;
  const float* M = mats.m[v];
  const float M0 = M[0], M1 = M[1], M2 = M[2],  M3  = M[3];
  const float M4 = M[4], M5 = M[5], M6 = M[6],  M7  = M[7];
  const float M8 = M[8], M9 = M[9], M10 = M[10], M11 = M[11];

  // ---- Phase 0: zmin/zmax partial over this block's 256-point slice ----
  if (tid < 256) {
    const int p = lin * 256 + tid;
    float x = data[3*p+0], y = data[3*p+1], zz = data[3*p+2];
    float z = M8*x + M9*y + M10*zz + M11;
    float zmn = z, zmx = z;
#pragma unroll
    for (int m = 32; m >= 1; m >>= 1) {
      zmn = fminf(zmn, __shfl_xor(zmn, m, 64));
      zmx = fmaxf(zmx, __shfl_xor(zmx, m, 64));
    }
    if (lane == 0) { smn[wid] = zmn; smx[wid] = zmx; }
  }
  __syncthreads();
  if (tid == 0) {
    red[lin] = fminf(fminf(smn[0], smn[1]), fminf(smn[2], smn[3]));
    red[NBLOCKS + lin] = fmaxf(fmaxf(smx[0], smx[1]), fmaxf(smx[2], smx[3]));
  }

  cg::this_grid().sync();

  // ---- Phase 1: global reduce (wave 0) + canvas init (all) ----
  for (int i = tid; i < CANVAS_W; i += THREADS) canvas[i] = 0u;
  if (tid < 64) {
    float a = INFINITY, c = -INFINITY;
#pragma unroll
    for (int k = 0; k < NBLOCKS / 64; ++k) {
      a = fminf(a, red[tid + 64 * k]);
      c = fmaxf(c, red[NBLOCKS + tid + 64 * k]);
    }
#pragma unroll
    for (int m = 32; m >= 1; m >>= 1) {
      a = fminf(a, __shfl_xor(a, m, 64));
      c = fmaxf(c, __shfl_xor(c, m, 64));
    }
    if (tid == 0) { zred[0] = a; zred[1] = c; qcnt = 0; }
  }
  __syncthreads();

  const float zmin = zred[0];
  const float zinv = 1.0f / (zred[1] - zmin);

  // ---- Phase A: sweep this batch's 4096 points ----
  const float2* src2 = (const float2*)(data + (size_t)b * NPER * 3);
#pragma unroll 1
  for (int chunk = 0; chunk < 2; ++chunk) {
    int f2base = chunk * 3072 + 3 * tid;      // 2048 pts per pass
    float2 A = src2[f2base], Bv = src2[f2base + 1], Cv = src2[f2base + 2];
    float px[2] = {A.x, Bv.y};
    float py[2] = {A.y, Cv.x};
    float pw[2] = {Bv.x, Cv.y};
#pragma unroll
    for (int k = 0; k < 2; ++k) {
      float x = px[k], y = py[k], zz = pw[k];
      float h1 = M4*x + M5*y + M6*zz + M7;
      float pif = (-h1 * 0.5f + 0.5f) * (float)(IMG_H - 1);
      int base_i = (int)floorf(pif);
      int i0 = max(max(base_i - 9, 0), si0);
      int i1 = min(min(base_i + 10, IMG_H - 1), si0 + (STRIP - 1));
      float h0 = M0*x + M1*y + M2*zz + M3;
      float pjf = (h0 * 0.5f + 0.5f) * (float)(IMG_W - 1);
      int base_j = (int)floorf(pjf);
      bool hit = (i0 <= i1) & (base_j >= -10) & (base_j <= IMG_W + 8);

      unsigned long long m = __ballot(hit);
      int cnt = __popcll(m);
      int wbase = 0;
      if (lane == 0 && cnt) wbase = atomicAdd(&qcnt, cnt);
      wbase = __shfl(wbase, 0);
      if (hit) {
        float h2 = M8*x + M9*y + M10*zz + M11;
        float feat = fmaxf(1.0f - (h2 - zmin) * zinv, 0.0f);   // >=0: bit-max ok
        int rows = i1 - i0 + 1;                                // 1..16
        int basew = (i0 - si0) * ROWW + (base_j + 10);         // [0, 4759]
        unsigned meta = ((unsigned)rows << 13) | (unsigned)basew;
        float fi_s = ((float)i0 - pif) * KC;
        float fj_s = ((float)(base_j - 9) - pjf) * KC;
        int slot = wbase + (int)__popcll(m & ((1ull << lane) - 1));
        if (slot < CAP)
          q4[slot] = make_float4(fi_s, fj_s, feat, __uint_as_float(meta));
      }
    }
  }
  __syncthreads();

  // ---- Phase B: drain ----
  const int n = min(qcnt, CAP);
  const int r_l   = (lane * 3277) >> 16;      // exact lane/20 for lane < 64
  const int col_l = lane - r_l * 20;
  const float col_kc = (float)col_l * KC;
  const float r_kc   = (float)r_l * KC;

  if (lane < 60) {
    for (int e = wid; e < n; e += NWAVES) {
      float4 Q = q4[e];                       // uniform addr -> broadcast
      float fi_s = Q.x, fj_s = Q.y, feat = Q.z;
      unsigned meta = __float_as_uint(Q.w);
      int basew = (int)(meta & 0x1FFFu);
      int rows  = (int)(meta >> 13);
      float dy = col_kc + fj_s;
      float dy2 = dy * dy;
      float dx = r_kc + fi_s;
      unsigned int* ptr = canvas + (basew + r_l * ROWW + col_l);
      int rb = 0;
      for (; rb + 3 <= rows; rb += 3) {       // full 3-row iterations
        float t = fminf(__builtin_fmaf(dx, dx, dy2), TMAX);
        float w = __builtin_fmaf(t,
                    __builtin_fmaf(t,
                      __builtin_fmaf(t,
                        __builtin_fmaf(t, 2.4801587e-5f, -1.3888889e-3f),
                        4.1666668e-2f),
                      -0.5f),
                    1.0f);
        atomicMax(ptr, __float_as_uint(w * feat));
        dx += KC3;
        ptr += 3 * ROWW;
      }
      if (rb < rows) {                        // tail: idempotent row clamp
        int row = min(rb + r_l, rows - 1);
        float dxt = __builtin_fmaf((float)row, KC, fi_s);
        float t = fminf(__builtin_fmaf(dxt, dxt, dy2), TMAX);
        float w = __builtin_fmaf(t,
                    __builtin_fmaf(t,
                      __builtin_fmaf(t,
                        __builtin_fmaf(t, 2.4801587e-5f, -1.3888889e-3f),
                        4.1666668e-2f),
                      -0.5f),
                    1.0f);
        atomicMax(canvas + (basew + row * ROWW + col_l),
                  __float_as_uint(w * feat));
      }
    }
  }

  __syncthreads();
  float* outb = out + ((size_t)b * IMG_H + si0) * IMG_W;
#pragma unroll
  for (int i = tid; i < STRIP * IMG_W; i += THREADS) {
    int r = i >> 8, col = i & 255;
    outb[i] = __uint_as_float(canvas[r * ROWW + PADL + col]);
  }
}

extern "C" void kernel_launch(void* const* d_in, const int* in_sizes, int n_in,
                              void* d_out, int out_size, void* d_ws, size_t ws_size,
                              hipStream_t stream) {
  const float* data = (const float*)d_in[0];
  const int* view_id = (const int*)d_in[1];
  float* out = (float*)d_out;
  float* red = (float*)d_ws;

  Mats mats;
  build_mats(mats.m);

  dim3 grid(NSTRIPS, NBATCH);
  dim3 block(THREADS);
  void* args[] = {(void*)&data, (void*)&view_id, (void*)&mats,
                  (void*)&red, (void*)&out};
  hipLaunchCooperativeKernel((const void*)splat_coop, grid, block,
                             args, 0, stream);
}

// Round 15
// 35.368 us; speedup vs baseline: 2.2380x; 2.2380x over previous
//
#include <hip/hip_runtime.h>
#include <math.h>

#define IMG_H 256
#define IMG_W 256
#define NBATCH 32
#define NPER 4096
#define NPTS (NBATCH * NPER)
#define STRIP 16
#define NSTRIPS (IMG_H / STRIP)      // 16
#define THREADS 1024
#define NWAVES (THREADS / 64)        // 16
#define PADL 19
#define ROWW 299                     // mod 32 = 11 -> adjacent rows on distant banks
#define CANVAS_W (STRIP * ROWW)      // 4784 words (19.1 KB)
#define KC  0.15707964f              // pi/20
#define KC3 0.47123890f              // 3*KC
#define TMAX 2.4674011f              // (pi/2)^2
#define BBLK 512                     // bin_agg blocks (256 pts each, 16/batch)
#define WPB 16                       // windows per bin = producer blocks per batch
#define WCAP 256                     // slots per window (<= points per block)
#define SCH 1024                     // drain LDS stage chunk (16 KB)

// d_ws layout (bytes):
//   [0, 32768)       : u32 counts[512][16]   (block x strip, plain stores)
//   [65536, 69632)   : f32 zmin[512] + zmax[512] partials
//   [131072, ...)    : float4 records, 512 bins * 16 windows * 256 * 16 B = 32 MiB

// 8 views, rows 0..2 of M (row 3 is [0,0,0,1] -> w==1).
struct Mats { float m[8][12]; };

static void build_mats(float out[8][12]) {
  static const double EYES[8][3] = {
    {-1,-1,-1},{-1,-1, 1},{-1, 1,-1},{-1, 1, 1},
    { 1,-1,-1},{ 1,-1, 1},{ 1, 1,-1},{ 1, 1, 1}};
  for (int v = 0; v < 8; ++v) {
    const double* e = EYES[v];
    double en = sqrt(e[0]*e[0] + e[1]*e[1] + e[2]*e[2]);
    if (en < 1e-6) en = 1e-6;
    double z[3] = {e[0]/en, e[1]/en, e[2]/en};
    double x[3] = {-z[1], z[0], 0.0};
    double xn = sqrt(x[0]*x[0] + x[1]*x[1]);
    if (xn < 1e-6) xn = 1e-6;
    x[0] /= xn; x[1] /= xn; x[2] = 0.0;
    double y[3] = {z[1]*x[2] - z[2]*x[1],
                   z[2]*x[0] - z[0]*x[2],
                   z[0]*x[1] - z[1]*x[0]};
    const double s  = 1.5;
    const double pz = -2.0 / (10.0 - 0.1);
    const double c3 = (10.0 + 0.1) / (10.0 - 0.1);
    double dxe = x[0]*e[0] + x[1]*e[1] + x[2]*e[2];
    double dye = y[0]*e[0] + y[1]*e[1] + y[2]*e[2];
    double dze = z[0]*e[0] + z[1]*e[1] + z[2]*e[2];
    out[v][0] = (float)(s*x[0]); out[v][1] = (float)(s*x[1]);
    out[v][2] = (float)(s*x[2]); out[v][3] = (float)(-s*dxe);
    out[v][4] = (float)(s*y[0]); out[v][5] = (float)(s*y[1]);
    out[v][6] = (float)(s*y[2]); out[v][7] = (float)(-s*dye);
    out[v][8] = (float)(pz*z[0]); out[v][9] = (float)(pz*z[1]);
    out[v][10] = (float)(pz*z[2]); out[v][11] = (float)(-pz*dze + c3);
  }
}

// 512 blocks x 256 threads, one point/thread. Atomic-free global binning:
// each (block,strip) owns a static 256-slot window. Per-WAVE sub-histograms
// (hist[4][17], padded) cut LDS same-address atomic depth 4x; a 64-lane
// scan merges them into window-local slot bases. Counts are plain stores.
// Also folds the zmin/zmax partial reduction.
__global__ __launch_bounds__(256)
void bin_agg(const float* __restrict__ data,
             const int* __restrict__ view_id,
             Mats mats, unsigned int* __restrict__ counts,
             float4* __restrict__ rec, float* __restrict__ red) {
  __shared__ unsigned int hist[4][17];
  __shared__ unsigned int wbase[4][17];
  __shared__ float smn[4], smx[4];

  const int tid  = threadIdx.x;
  const int w    = tid >> 6;           // wave id 0..3
  const int blk  = blockIdx.x;
  const int b    = blk >> 4;           // 16 blocks per batch
  const int kblk = blk & 15;
  const int p    = blk * 256 + tid;

  if (tid < 68) ((unsigned int*)hist)[tid] = 0u;
  __syncthreads();

  const int v = (*view_id) & 7;
  const float* M = mats.m[v];
  float x = data[3*p+0], y = data[3*p+1], zz = data[3*p+2];
  float h1 = M[4]*x + M[5]*y + M[6]*zz + M[7];
  float pif = (-h1 * 0.5f + 0.5f) * (float)(IMG_H - 1);
  int base_i = (int)floorf(pif);
  int lo = max(base_i - 9, 0), hi = min(base_i + 10, IMG_H - 1);
  float h0 = M[0]*x + M[1]*y + M[2]*zz + M[3];
  float pjf = (h0 * 0.5f + 0.5f) * (float)(IMG_W - 1);
  int base_j = (int)floorf(pjf);
  float h2 = M[8]*x + M[9]*y + M[10]*zz + M[11];  // needed for ALL points

  bool valid = (lo <= hi) & (base_j >= -10) & (base_j <= IMG_W + 8);
  int s0 = lo >> 4, s1 = valid ? (hi >> 4) : (lo >> 4) - 1;

  // local slot reservation in this wave's sub-histogram (max 3 fragments)
  unsigned fr0 = 0xFFFFFFFFu, fr1 = 0xFFFFFFFFu, fr2 = 0xFFFFFFFFu;
  if (valid) {
    fr0 = atomicAdd(&hist[w][s0], 1u) | ((unsigned)s0 << 16);
    if (s0 + 1 <= s1) fr1 = atomicAdd(&hist[w][s0 + 1], 1u) | ((unsigned)(s0 + 1) << 16);
    if (s0 + 2 <= s1) fr2 = atomicAdd(&hist[w][s0 + 2], 1u) | ((unsigned)(s0 + 2) << 16);
  }

  // block zmin/zmax partial (over all points incl. off-screen)
  float zmn = h2, zmx = h2;
#pragma unroll
  for (int m = 32; m >= 1; m >>= 1) {
    zmn = fminf(zmn, __shfl_xor(zmn, m, 64));
    zmx = fmaxf(zmx, __shfl_xor(zmx, m, 64));
  }
  if ((tid & 63) == 0) { smn[w] = zmn; smx[w] = zmx; }

  __syncthreads();

  // merge sub-histograms: 64 lanes = (strip s = tid>>2, wave ww = tid&3);
  // prefix over ww within each s gives window-local wave bases.
  if (tid < 64) {
    int s = tid >> 2, ww = tid & 3;
    unsigned val = hist[ww][s];
    unsigned acc = val;
#pragma unroll
    for (int d = 1; d < 4; d <<= 1) {
      unsigned t = __shfl_up(acc, d, 64);
      if (ww >= d) acc += t;
    }
    wbase[ww][s] = acc - val;                   // exclusive over waves
    if (ww == 3) counts[blk * NSTRIPS + s] = acc;  // total, plain store
  }
  if (tid == 64) {
    red[blk] = fminf(fminf(smn[0], smn[1]), fminf(smn[2], smn[3]));
    red[BBLK + blk] = fmaxf(fmaxf(smx[0], smx[1]), fmaxf(smx[2], smx[3]));
  }
  __syncthreads();

  // scatter to static windows (base is static arithmetic, no global atomics)
  if (valid) {
    float fj_s = ((float)(base_j - 9) - pjf) * KC;
#pragma unroll
    for (int k = 0; k < 3; ++k) {
      unsigned fr = (k == 0) ? fr0 : (k == 1) ? fr1 : fr2;
      if (fr != 0xFFFFFFFFu) {
        int s = (int)(fr >> 16);
        unsigned idx = wbase[w][s] + (fr & 0xFFFFu);           // < 256 always
        int i0 = max(lo, s * STRIP);
        int i1 = min(hi, s * STRIP + (STRIP - 1));
        int rows = i1 - i0 + 1;                                // 1..16
        int basew = (i0 - s * STRIP) * ROWW + (base_j + 10);   // <= 4759
        unsigned meta = ((unsigned)rows << 13) | (unsigned)basew;
        float fi_s = ((float)i0 - pif) * KC;
        rec[((size_t)(b * NSTRIPS + s) * WPB + kblk) * WCAP + idx] =
            make_float4(fi_s, fj_s, h2, __uint_as_float(meta));
      }
    }
  }
}

// Pure drain: one block per (batch, 16-row strip), 1024 threads. 16 window
// counts -> in-wave prefix scan -> segmented coalesced staging into
// contiguous LDS -> waves consume entries via broadcast ds_read_b128
// (60 lanes = 3 rows x 20 cols). Per-cell: degree-4 poly (>= 3.3e-5 on
// [0,TMAX] -> val >= 0, bit-max safe), circle-masked atomic (corner cells
// generate no DS traffic). NOTE: deg-3 poly is NEGATIVE near TMAX and
// poisons the uint max via the sign bit (R13 failure) — keep deg-4.
__global__ __launch_bounds__(THREADS, 8)
void splat_drain(const unsigned int* __restrict__ counts,
                 const float4* __restrict__ rec,
                 const float* __restrict__ red,
                 float* __restrict__ out) {
  __shared__ unsigned int canvas[CANVAS_W];   // 19136 B
  __shared__ float4 stage[SCH];               // 16 KB
  __shared__ int off[WPB + 1];
  __shared__ int c16[WPB];
  __shared__ float zred[2];

  const int tid  = threadIdx.x;
  const int lane = tid & 63;
  const int wid  = tid >> 6;
  const int b    = blockIdx.y;
  const int strip = (blockIdx.x * 7 + b) & 15;
  const int bin  = b * NSTRIPS + strip;

  // issue window-count loads first so HBM latency hides under canvas init
  int cload = 0;
  if (tid >= 64 && tid < 80)
    cload = (int)counts[(b * WPB + (tid - 64)) * NSTRIPS + strip];

  for (int i = tid; i < CANVAS_W; i += THREADS) canvas[i] = 0u;

  if (tid < 64) {   // wave 0 reduces the 512+512 zmin/zmax partials
    float a = INFINITY, c = -INFINITY;
#pragma unroll
    for (int k = 0; k < BBLK / 64; ++k) {
      a = fminf(a, red[tid + 64 * k]);
      c = fmaxf(c, red[BBLK + tid + 64 * k]);
    }
#pragma unroll
    for (int m = 32; m >= 1; m >>= 1) {
      a = fminf(a, __shfl_xor(a, m, 64));
      c = fmaxf(c, __shfl_xor(c, m, 64));
    }
    if (tid == 0) { zred[0] = a; zred[1] = c; }
  } else if (tid >= 64 && tid < 80) {  // wave 1: counts + prefix scan
    int k = tid - 64;
    int c = cload;
    int s = c;
#pragma unroll
    for (int d = 1; d < 16; d <<= 1) {
      int y2 = __shfl_up(s, d, 64);
      if (k >= d) s += y2;
    }
    off[k] = s - c;
    c16[k] = c;
    if (k == 15) off[16] = s;
  }
  __syncthreads();

  const float zmin = zred[0];
  const float zinv = 1.0f / (zred[1] - zmin);
  const int n = off[16];

  // fixed per-lane drain geometry: r_l in {0,1,2}, col_l in [0,20)
  const int r_l   = (lane * 3277) >> 16;      // exact lane/20 for lane < 64
  const int col_l = lane - r_l * 20;
  const float col_kc = (float)col_l * KC;
  const float r_kc   = (float)r_l * KC;

  // staging assignment: 16 groups of 64 threads, one window each
  const int g16 = tid >> 6;
  const int l64 = tid & 63;
  const float4* win = rec + ((size_t)bin * WPB + g16) * WCAP;
  const int wlo = off[g16];
  const int whi = wlo + c16[g16];

  for (int c0 = 0; c0 < n; c0 += SCH) {
    const int cend = min(c0 + SCH, n);
    if (c0) __syncthreads();                  // prev chunk fully consumed
    {
      int lo = max(wlo, c0), hi2 = min(whi, cend);
      for (int g = lo + l64; g < hi2; g += 64)
        stage[g - c0] = win[g - wlo];
    }
    __syncthreads();

    const int m = cend - c0;
    if (lane < 60) {
      for (int e = wid; e < m; e += NWAVES) {
        float4 Q = stage[e];                  // uniform addr -> broadcast
        float fi_s = Q.x, fj_s = Q.y;
        unsigned meta = __float_as_uint(Q.w);
        float feat = fmaxf(1.0f - (Q.z - zmin) * zinv, 0.0f);  // >=0: bit-max ok
        int basew = (int)(meta & 0x1FFFu);
        int rows  = (int)(meta >> 13);
        float dy = col_kc + fj_s;
        float dy2 = dy * dy;
        float dx = r_kc + fi_s;
        unsigned int* ptr = canvas + (basew + r_l * ROWW + col_l);
        int rb = 0;
        for (; rb + 3 <= rows; rb += 3) {     // full 3-row iterations
          float t = __builtin_fmaf(dx, dx, dy2);
          // cos(sqrt(t)) deg-4: 1 - t/2 + t^2/24 - t^3/720 + t^4/40320
          // >= 3.3e-5 on [0, TMAX] -> w*feat >= 0 (uint-max safe)
          float w = __builtin_fmaf(t,
                      __builtin_fmaf(t,
                        __builtin_fmaf(t,
                          __builtin_fmaf(t, 2.4801587e-5f, -1.3888889e-3f),
                          4.1666668e-2f),
                        -0.5f),
                      1.0f);
          if (t < TMAX)                       // circle mask: no DS op outside
            atomicMax(ptr, __float_as_uint(w * feat));
          dx += KC3;
          ptr += 3 * ROWW;
        }
        if (rb < rows) {                      // tail: idempotent row clamp
          int row = min(rb + r_l, rows - 1);
          float dxt = __builtin_fmaf((float)row, KC, fi_s);
          float t = __builtin_fmaf(dxt, dxt, dy2);
          float w = __builtin_fmaf(t,
                      __builtin_fmaf(t,
                        __builtin_fmaf(t,
                          __builtin_fmaf(t, 2.4801587e-5f, -1.3888889e-3f),
                          4.1666668e-2f),
                        -0.5f),
                      1.0f);
          if (t < TMAX)
            atomicMax(canvas + (basew + row * ROWW + col_l),
                      __float_as_uint(w * feat));
        }
      }
    }
  }

  __syncthreads();
  float* outb = out + ((size_t)b * IMG_H + strip * STRIP) * IMG_W;
#pragma unroll
  for (int i = tid; i < STRIP * IMG_W; i += THREADS) {
    int r = i >> 8, col = i & 255;
    outb[i] = __uint_as_float(canvas[r * ROWW + PADL + col]);
  }
}

extern "C" void kernel_launch(void* const* d_in, const int* in_sizes, int n_in,
                              void* d_out, int out_size, void* d_ws, size_t ws_size,
                              hipStream_t stream) {
  const float* data = (const float*)d_in[0];
  const int* view_id = (const int*)d_in[1];
  float* out = (float*)d_out;

  unsigned int* counts = (unsigned int*)d_ws;                    // 32 KB
  float* red = (float*)((char*)d_ws + 65536);                    // 4 KB
  float4* rec = (float4*)((char*)d_ws + 131072);                 // 32 MiB

  Mats mats;
  build_mats(mats.m);

  bin_agg<<<BBLK, 256, 0, stream>>>(data, view_id, mats, counts, rec, red);
  dim3 grid(NSTRIPS, NBATCH);
  splat_drain<<<grid, THREADS, 0, stream>>>(counts, rec, red, out);
}

// Round 16
// 33.045 us; speedup vs baseline: 2.3953x; 1.0703x over previous
//
#include <hip/hip_runtime.h>
#include <math.h>

#define IMG_H 256
#define IMG_W 256
#define NBATCH 32
#define NPER 4096
#define NPTS (NBATCH * NPER)
#define STRIP 16
#define NSTRIPS (IMG_H / STRIP)      // 16
#define THREADS 1024
#define NWAVES (THREADS / 64)        // 16
#define PADL 19
#define ROWW 299                     // mod 32 = 11 -> adjacent rows on distant banks
#define CANVAS_W (STRIP * ROWW)      // 4784 words (19.1 KB)
#define KC  0.15707964f              // pi/20
#define KC3 0.47123890f              // 3*KC
#define TMAX 2.4674011f              // (pi/2)^2 : poly(t) >= 3.3e-5 on [0,TMAX]
#define BBLK 512                     // bin_agg blocks (256 pts each, 16/batch)
#define WPB 16                       // windows per bin = producer blocks per batch
#define WCAP 256                     // slots per window (<= points per block)
#define SCH 1024                     // drain LDS stage chunk (16 KB)

// d_ws layout (bytes):
//   [0, 32768)       : u32 counts[512][16]   (block x strip, plain stores)
//   [65536, 69632)   : f32 zmin[512] + zmax[512] partials
//   [131072, ...)    : float4 records, 512 bins * 16 windows * 256 * 16 B = 32 MiB

// 8 views, rows 0..2 of M (row 3 is [0,0,0,1] -> w==1).
struct Mats { float m[8][12]; };

static void build_mats(float out[8][12]) {
  static const double EYES[8][3] = {
    {-1,-1,-1},{-1,-1, 1},{-1, 1,-1},{-1, 1, 1},
    { 1,-1,-1},{ 1,-1, 1},{ 1, 1,-1},{ 1, 1, 1}};
  for (int v = 0; v < 8; ++v) {
    const double* e = EYES[v];
    double en = sqrt(e[0]*e[0] + e[1]*e[1] + e[2]*e[2]);
    if (en < 1e-6) en = 1e-6;
    double z[3] = {e[0]/en, e[1]/en, e[2]/en};
    double x[3] = {-z[1], z[0], 0.0};
    double xn = sqrt(x[0]*x[0] + x[1]*x[1]);
    if (xn < 1e-6) xn = 1e-6;
    x[0] /= xn; x[1] /= xn; x[2] = 0.0;
    double y[3] = {z[1]*x[2] - z[2]*x[1],
                   z[2]*x[0] - z[0]*x[2],
                   z[0]*x[1] - z[1]*x[0]};
    const double s  = 1.5;
    const double pz = -2.0 / (10.0 - 0.1);
    const double c3 = (10.0 + 0.1) / (10.0 - 0.1);
    double dxe = x[0]*e[0] + x[1]*e[1] + x[2]*e[2];
    double dye = y[0]*e[0] + y[1]*e[1] + y[2]*e[2];
    double dze = z[0]*e[0] + z[1]*e[1] + z[2]*e[2];
    out[v][0] = (float)(s*x[0]); out[v][1] = (float)(s*x[1]);
    out[v][2] = (float)(s*x[2]); out[v][3] = (float)(-s*dxe);
    out[v][4] = (float)(s*y[0]); out[v][5] = (float)(s*y[1]);
    out[v][6] = (float)(s*y[2]); out[v][7] = (float)(-s*dye);
    out[v][8] = (float)(pz*z[0]); out[v][9] = (float)(pz*z[1]);
    out[v][10] = (float)(pz*z[2]); out[v][11] = (float)(-pz*dze + c3);
  }
}

// 512 blocks x 256 threads, one point/thread. Atomic-free global binning:
// each (block,strip) owns a static 256-slot window. Per-WAVE sub-histograms
// (hist[4][17], padded) cut LDS same-address atomic depth 4x; a 64-lane
// scan merges them into window-local slot bases. Counts are plain stores.
// Also folds the zmin/zmax partial reduction.
__global__ __launch_bounds__(256)
void bin_agg(const float* __restrict__ data,
             const int* __restrict__ view_id,
             Mats mats, unsigned int* __restrict__ counts,
             float4* __restrict__ rec, float* __restrict__ red) {
  __shared__ unsigned int hist[4][17];
  __shared__ unsigned int wbase[4][17];
  __shared__ float smn[4], smx[4];

  const int tid  = threadIdx.x;
  const int w    = tid >> 6;           // wave id 0..3
  const int blk  = blockIdx.x;
  const int b    = blk >> 4;           // 16 blocks per batch
  const int kblk = blk & 15;
  const int p    = blk * 256 + tid;

  if (tid < 68) ((unsigned int*)hist)[tid] = 0u;
  __syncthreads();

  const int v = (*view_id) & 7;
  const float* M = mats.m[v];
  float x = data[3*p+0], y = data[3*p+1], zz = data[3*p+2];
  float h1 = M[4]*x + M[5]*y + M[6]*zz + M[7];
  float pif = (-h1 * 0.5f + 0.5f) * (float)(IMG_H - 1);
  int base_i = (int)floorf(pif);
  int lo = max(base_i - 9, 0), hi = min(base_i + 10, IMG_H - 1);
  float h0 = M[0]*x + M[1]*y + M[2]*zz + M[3];
  float pjf = (h0 * 0.5f + 0.5f) * (float)(IMG_W - 1);
  int base_j = (int)floorf(pjf);
  float h2 = M[8]*x + M[9]*y + M[10]*zz + M[11];  // needed for ALL points

  bool valid = (lo <= hi) & (base_j >= -10) & (base_j <= IMG_W + 8);
  int s0 = lo >> 4, s1 = valid ? (hi >> 4) : (lo >> 4) - 1;

  // local slot reservation in this wave's sub-histogram (max 3 fragments)
  unsigned fr0 = 0xFFFFFFFFu, fr1 = 0xFFFFFFFFu, fr2 = 0xFFFFFFFFu;
  if (valid) {
    fr0 = atomicAdd(&hist[w][s0], 1u) | ((unsigned)s0 << 16);
    if (s0 + 1 <= s1) fr1 = atomicAdd(&hist[w][s0 + 1], 1u) | ((unsigned)(s0 + 1) << 16);
    if (s0 + 2 <= s1) fr2 = atomicAdd(&hist[w][s0 + 2], 1u) | ((unsigned)(s0 + 2) << 16);
  }

  // block zmin/zmax partial (over all points incl. off-screen)
  float zmn = h2, zmx = h2;
#pragma unroll
  for (int m = 32; m >= 1; m >>= 1) {
    zmn = fminf(zmn, __shfl_xor(zmn, m, 64));
    zmx = fmaxf(zmx, __shfl_xor(zmx, m, 64));
  }
  if ((tid & 63) == 0) { smn[w] = zmn; smx[w] = zmx; }

  __syncthreads();

  // merge sub-histograms: 64 lanes = (strip s = tid>>2, wave ww = tid&3);
  // prefix over ww within each s gives window-local wave bases.
  if (tid < 64) {
    int s = tid >> 2, ww = tid & 3;
    unsigned val = hist[ww][s];
    unsigned acc = val;
#pragma unroll
    for (int d = 1; d < 4; d <<= 1) {
      unsigned t = __shfl_up(acc, d, 64);
      if (ww >= d) acc += t;
    }
    wbase[ww][s] = acc - val;                   // exclusive over waves
    if (ww == 3) counts[blk * NSTRIPS + s] = acc;  // total, plain store
  }
  if (tid == 64) {
    red[blk] = fminf(fminf(smn[0], smn[1]), fminf(smn[2], smn[3]));
    red[BBLK + blk] = fmaxf(fmaxf(smx[0], smx[1]), fmaxf(smx[2], smx[3]));
  }
  __syncthreads();

  // scatter to static windows (base is static arithmetic, no global atomics)
  if (valid) {
    float fj_s = ((float)(base_j - 9) - pjf) * KC;
#pragma unroll
    for (int k = 0; k < 3; ++k) {
      unsigned fr = (k == 0) ? fr0 : (k == 1) ? fr1 : fr2;
      if (fr != 0xFFFFFFFFu) {
        int s = (int)(fr >> 16);
        unsigned idx = wbase[w][s] + (fr & 0xFFFFu);           // < 256 always
        int i0 = max(lo, s * STRIP);
        int i1 = min(hi, s * STRIP + (STRIP - 1));
        int rows = i1 - i0 + 1;                                // 1..16
        int basew = (i0 - s * STRIP) * ROWW + (base_j + 10);   // <= 4759
        unsigned meta = ((unsigned)rows << 13) | (unsigned)basew;
        float fi_s = ((float)i0 - pif) * KC;
        rec[((size_t)(b * NSTRIPS + s) * WPB + kblk) * WCAP + idx] =
            make_float4(fi_s, fj_s, h2, __uint_as_float(meta));
      }
    }
  }
}

// Pure drain: one block per (batch, 16-row strip), 1024 threads. 16 window
// counts -> in-wave prefix scan -> segmented coalesced staging into
// contiguous LDS (usually ONE chunk) -> waves consume entries via broadcast
// ds_read_b128 (60 lanes = 3 rows x 20 cols, branchless, incremental
// dx/pointer, idempotent row-clamp tail). Deg-4 poly clamped at TMAX is
// >= 3.3e-5 -> val >= 0 -> uint bit-max valid (deg-3 goes negative: R13 bug).
__global__ __launch_bounds__(THREADS, 8)
void splat_drain(const unsigned int* __restrict__ counts,
                 const float4* __restrict__ rec,
                 const float* __restrict__ red,
                 float* __restrict__ out) {
  __shared__ unsigned int canvas[CANVAS_W];   // 19136 B
  __shared__ float4 stage[SCH];               // 16 KB
  __shared__ int off[WPB + 1];
  __shared__ int c16[WPB];
  __shared__ float zred[2];

  const int tid  = threadIdx.x;
  const int lane = tid & 63;
  const int wid  = tid >> 6;
  const int b    = blockIdx.y;
  const int strip = (blockIdx.x * 7 + b) & 15;  // stride-7 bijection
  const int bin  = b * NSTRIPS + strip;

  for (int i = tid; i < CANVAS_W; i += THREADS) canvas[i] = 0u;

  if (tid < 64) {   // wave 0 reduces the 512+512 zmin/zmax partials
    float a = INFINITY, c = -INFINITY;
#pragma unroll
    for (int k = 0; k < BBLK / 64; ++k) {
      a = fminf(a, red[tid + 64 * k]);
      c = fmaxf(c, red[BBLK + tid + 64 * k]);
    }
#pragma unroll
    for (int m = 32; m >= 1; m >>= 1) {
      a = fminf(a, __shfl_xor(a, m, 64));
      c = fmaxf(c, __shfl_xor(c, m, 64));
    }
    if (tid == 0) { zred[0] = a; zred[1] = c; }
  } else if (tid >= 64 && tid < 80) {  // wave 1: counts + prefix scan
    int k = tid - 64;
    int c = (int)counts[(b * WPB + k) * NSTRIPS + strip];
    int s = c;
#pragma unroll
    for (int d = 1; d < 16; d <<= 1) {
      int y2 = __shfl_up(s, d, 64);
      if (k >= d) s += y2;
    }
    off[k] = s - c;
    c16[k] = c;
    if (k == 15) off[16] = s;
  }
  __syncthreads();

  const float zmin = zred[0];
  const float zinv = 1.0f / (zred[1] - zmin);
  const int n = off[16];

  // fixed per-lane drain geometry: r_l in {0,1,2}, col_l in [0,20)
  const int r_l   = (lane * 3277) >> 16;      // exact lane/20 for lane < 64
  const int col_l = lane - r_l * 20;
  const float col_kc = (float)col_l * KC;
  const float r_kc   = (float)r_l * KC;

  // staging assignment: 16 groups of 64 threads, one window each
  const int g16 = tid >> 6;
  const int l64 = tid & 63;
  const float4* win = rec + ((size_t)bin * WPB + g16) * WCAP;
  const int wlo = off[g16];
  const int whi = wlo + c16[g16];

  for (int c0 = 0; c0 < n; c0 += SCH) {
    const int cend = min(c0 + SCH, n);
    if (c0) __syncthreads();                  // prev chunk fully consumed
    {
      int lo = max(wlo, c0), hi2 = min(whi, cend);
      for (int g = lo + l64; g < hi2; g += 64)
        stage[g - c0] = win[g - wlo];
    }
    __syncthreads();

    const int m = cend - c0;
    if (lane < 60) {
      for (int e = wid; e < m; e += NWAVES) {
        float4 Q = stage[e];                  // uniform addr -> broadcast
        float fi_s = Q.x, fj_s = Q.y;
        unsigned meta = __float_as_uint(Q.w);
        float feat = fmaxf(1.0f - (Q.z - zmin) * zinv, 0.0f);  // >=0: bit-max ok
        int basew = (int)(meta & 0x1FFFu);
        int rows  = (int)(meta >> 13);
        float dy = col_kc + fj_s;
        float dy2 = dy * dy;
        float dx = r_kc + fi_s;
        unsigned int* ptr = canvas + (basew + r_l * ROWW + col_l);
        int rb = 0;
        for (; rb + 3 <= rows; rb += 3) {     // full 3-row iterations
          float t = fminf(__builtin_fmaf(dx, dx, dy2), TMAX);
          float w = __builtin_fmaf(t,
                      __builtin_fmaf(t,
                        __builtin_fmaf(t,
                          __builtin_fmaf(t, 2.4801587e-5f, -1.3888889e-3f),
                          4.1666668e-2f),
                        -0.5f),
                      1.0f);
          atomicMax(ptr, __float_as_uint(w * feat));
          dx += KC3;
          ptr += 3 * ROWW;
        }
        if (rb < rows) {                      // tail: idempotent row clamp
          int row = min(rb + r_l, rows - 1);
          float dxt = __builtin_fmaf((float)row, KC, fi_s);
          float t = fminf(__builtin_fmaf(dxt, dxt, dy2), TMAX);
          float w = __builtin_fmaf(t,
                      __builtin_fmaf(t,
                        __builtin_fmaf(t,
                          __builtin_fmaf(t, 2.4801587e-5f, -1.3888889e-3f),
                          4.1666668e-2f),
                        -0.5f),
                      1.0f);
          atomicMax(canvas + (basew + row * ROWW + col_l),
                    __float_as_uint(w * feat));
        }
      }
    }
  }

  __syncthreads();
  float* outb = out + ((size_t)b * IMG_H + strip * STRIP) * IMG_W;
#pragma unroll
  for (int i = tid; i < STRIP * IMG_W; i += THREADS) {
    int r = i >> 8, col = i & 255;
    outb[i] = __uint_as_float(canvas[r * ROWW + PADL + col]);
  }
}

extern "C" void kernel_launch(void* const* d_in, const int* in_sizes, int n_in,
                              void* d_out, int out_size, void* d_ws, size_t ws_size,
                              hipStream_t stream) {
  const float* data = (const float*)d_in[0];
  const int* view_id = (const int*)d_in[1];
  float* out = (float*)d_out;

  unsigned int* counts = (unsigned int*)d_ws;                    // 32 KB
  float* red = (float*)((char*)d_ws + 65536);                    // 4 KB
  float4* rec = (float4*)((char*)d_ws + 131072);                 // 32 MiB

  Mats mats;
  build_mats(mats.m);

  bin_agg<<<BBLK, 256, 0, stream>>>(data, view_id, mats, counts, rec, red);
  dim3 grid(NSTRIPS, NBATCH);
  splat_drain<<<grid, THREADS, 0, stream>>>(counts, rec, red, out);
}